// Round 1
// baseline (952.615 us; speedup 1.0000x reference)
//
#include <hip/hip_runtime.h>

#define L_SEQ   2048
#define NBATCH  4
#define DM      512
#define DS      16
#define DR      32
#define NROWS   (NBATCH * L_SEQ)   // 8192

// ws layout (float offsets)
#define WS_XC    0
#define WS_DT    4194304
#define WS_XDBL  8388608           // 8192 * 64
#define WS_WXT   8912896           // 512 * 64
#define WS_WDTT  8945664           // 32 * 512
// total 8962048 floats = 35.8 MB

// ---------------- transpose the two projection weights ----------------
__global__ void k_transpose(const float* __restrict__ Wx, const float* __restrict__ Wdt,
                            float* __restrict__ WxT, float* __restrict__ WdtT) {
    int idx = blockIdx.x * 256 + threadIdx.x;
    if (idx < DM * 64) {                 // WxT[d][j] = Wx[j][d]
        int d = idx >> 6, j = idx & 63;
        WxT[idx] = Wx[j * DM + d];
    }
    if (idx < DR * DM) {                 // WdtT[r][d] = Wdt[d][r]
        int r = idx >> 9, d = idx & 511;
        WdtT[idx] = Wdt[d * DR + r];
    }
}

// ---------------- depthwise causal conv1d (K=4) ----------------
__global__ void k_conv(const float* __restrict__ x, const float* __restrict__ convw,
                       const float* __restrict__ convb, float* __restrict__ xc) {
    int idx = blockIdx.x * 256 + threadIdx.x;      // over 4M elements
    int d   = idx & (DM - 1);
    int row = idx >> 9;
    int l   = row & (L_SEQ - 1);
    float4 w = ((const float4*)convw)[d];          // conv_w[d][0][0..3]
    float acc = convb[d];
    acc = fmaf(x[idx], w.w, acc);
    if (l >= 1) acc = fmaf(x[idx -     DM], w.z, acc);
    if (l >= 2) acc = fmaf(x[idx - 2 * DM], w.y, acc);
    if (l >= 3) acc = fmaf(x[idx - 3 * DM], w.x, acc);
    xc[idx] = acc;
}

// ---------------- proj1: x_dbl[row][j] = sum_d xc[row][d] * Wx[j][d] ----------------
// wave per 8 rows, lane = j (64 cols). xc loads are wave-uniform (scalar-load friendly).
__global__ void k_proj1(const float* __restrict__ xc, const float* __restrict__ WxT,
                        float* __restrict__ xdbl) {
    int wv = __builtin_amdgcn_readfirstlane((int)(threadIdx.x >> 6));
    int j  = threadIdx.x & 63;
    int rows_base = blockIdx.x * 32 + wv * 8;      // 256 blocks * 32 rows = 8192
    const float* xcrow = xc + (size_t)rows_base * DM;
    float acc[8] = {0.f, 0.f, 0.f, 0.f, 0.f, 0.f, 0.f, 0.f};
    #pragma unroll 4
    for (int d = 0; d < DM; ++d) {
        float w = WxT[d * 64 + j];
        #pragma unroll
        for (int ri = 0; ri < 8; ++ri)
            acc[ri] = fmaf(xcrow[ri * DM + d], w, acc[ri]);
    }
    #pragma unroll
    for (int ri = 0; ri < 8; ++ri)
        xdbl[(size_t)(rows_base + ri) * 64 + j] = acc[ri];
}

// ---------------- proj2 + softplus: dt[row][d] ----------------
__global__ void k_proj2(const float* __restrict__ xdbl, const float* __restrict__ WdtT,
                        const float* __restrict__ dtb, float* __restrict__ dtw) {
    int idx = blockIdx.x * 256 + threadIdx.x;      // over 4M
    int d   = idx & (DM - 1);
    int row = idx >> 9;
    const float* xr = xdbl + (size_t)row * 64;
    float z = dtb[d];
    #pragma unroll 8
    for (int r = 0; r < DR; ++r)
        z = fmaf(xr[r], WdtT[r * DM + d], z);
    // softplus = logaddexp(z, 0) = max(z,0) + log1p(exp(-|z|))
    float sp = fmaxf(z, 0.f) + log1pf(__expf(-fabsf(z)));
    dtw[idx] = sp;
}

// ---------------- selective scan: lane per (b, d, n) ----------------
// block = 64 threads = 4 chains of 16 states; grid = 512 blocks.
__global__ void __launch_bounds__(64) k_scan(
        const float* __restrict__ dtw, const float* __restrict__ xc,
        const float* __restrict__ xdbl, const float* __restrict__ A_log,
        const float* __restrict__ Dvec, float* __restrict__ out) {
    int lane = threadIdx.x;
    int n = lane & 15;
    int g = lane >> 4;
    int blk = blockIdx.x;             // 0..511
    int b   = blk >> 7;               // 0..3
    int d0  = (blk & 127) * 4;
    int d   = d0 + g;

    float a  = -__expf(A_log[d0 * DS + lane]);   // = -exp(A_log[d][n]) (coalesced)
    float Dv = Dvec[d];
    float h  = 0.f;
    int rowbase = b * L_SEQ;

    #pragma unroll 8
    for (int l = 0; l < L_SEQ; ++l) {
        int row = rowbase + l;
        float dtv = dtw[row * DM + d];
        float xcv = xc[row * DM + d];
        float bmv = xdbl[row * 64 + DR + n];        // B[row][n]
        float cv  = xdbl[row * 64 + DR + DS + n];   // C[row][n]
        float dA  = __expf(dtv * a);
        h = fmaf(dA, h, (dtv * xcv) * bmv);
        float p = h * cv;
        p += __shfl_xor(p, 1);
        p += __shfl_xor(p, 2);
        p += __shfl_xor(p, 4);
        p += __shfl_xor(p, 8);
        if (n == 0) out[row * DM + d] = fmaf(xcv, Dv, p);
    }
}

extern "C" void kernel_launch(void* const* d_in, const int* in_sizes, int n_in,
                              void* d_out, int out_size, void* d_ws, size_t ws_size,
                              hipStream_t stream) {
    const float* x      = (const float*)d_in[0];
    const float* A_log  = (const float*)d_in[1];
    const float* Dvec   = (const float*)d_in[2];
    const float* Wx     = (const float*)d_in[3];
    const float* Wdt    = (const float*)d_in[4];
    const float* dtb    = (const float*)d_in[5];
    const float* convw  = (const float*)d_in[6];
    const float* convb  = (const float*)d_in[7];
    float* out = (float*)d_out;
    float* ws  = (float*)d_ws;

    float* xc   = ws + WS_XC;
    float* dtw  = ws + WS_DT;
    float* xdbl = ws + WS_XDBL;
    float* WxT  = ws + WS_WXT;
    float* WdtT = ws + WS_WDTT;

    // transpose weights (128 blocks covers 32768 elems)
    k_transpose<<<128, 256, 0, stream>>>(Wx, Wdt, WxT, WdtT);
    // conv: 4M elems
    k_conv<<<16384, 256, 0, stream>>>(x, convw, convb, xc);
    // proj1: 8192 rows / 32 rows per block
    k_proj1<<<256, 256, 0, stream>>>(xc, WxT, xdbl);
    // proj2 + softplus: 4M elems
    k_proj2<<<16384, 256, 0, stream>>>(xdbl, WdtT, dtb, dtw);
    // scan: 512 blocks x 64 threads
    k_scan<<<512, 64, 0, stream>>>(dtw, xc, xdbl, A_log, Dvec, out);
}

// Round 2
// 289.319 us; speedup vs baseline: 3.2926x; 3.2926x over previous
//
#include <hip/hip_runtime.h>

#define L_SEQ   2048
#define NBATCH  4
#define DM      512
#define DS      16
#define DR      32
#define NCH     16            // chunks
#define CL      128           // chunk length = L_SEQ/NCH
#define NBDN    32768         // NBATCH*DM*DS chains

// ws layout (float offsets). P/S/Hin alias the xc (row-major) buffer, which is
// dead after k_proj1 (stream-ordered before k_pass1 runs).
#define WS_XC    0            // 4194304 floats (row-major xc; reused below)
#define WS_P     0            // 524288
#define WS_S     524288       // 524288
#define WS_HIN   1048576      // 524288
#define WS_XCT   4194304      // 4194304  xc_t[b][d][l]
#define WS_DTT   8388608      // 4194304  dt_t[b][d][l]
#define WS_XD32  12582912     // 262144   x_dbl dt-part [row][32]
#define WS_BT    12845056     // 131072   B_t[b][n][l]
#define WS_CT    12976128     // 131072   C_t[b][n][l]
#define WS_WXT   13107200     // 32768
#define WS_WDTT  13139968     // 16384
// total 13156352 floats = 52.6 MB

// ---------------- transpose the two projection weights ----------------
__global__ void k_transpose(const float* __restrict__ Wx, const float* __restrict__ Wdt,
                            float* __restrict__ WxT, float* __restrict__ WdtT) {
    int idx = blockIdx.x * 256 + threadIdx.x;
    if (idx < DM * 64) {                 // WxT[d][j] = Wx[j][d]
        int d = idx >> 6, j = idx & 63;
        WxT[idx] = Wx[j * DM + d];
    }
    if (idx < DR * DM) {                 // WdtT[r][d] = Wdt[d][r]
        int r = idx >> 9, d = idx & 511;
        WdtT[idx] = Wdt[d * DR + r];
    }
}

// ---------------- depthwise causal conv1d (K=4), row-major out ----------------
__global__ void k_conv(const float* __restrict__ x, const float* __restrict__ convw,
                       const float* __restrict__ convb, float* __restrict__ xc) {
    int idx = blockIdx.x * 256 + threadIdx.x;      // over 4M elements
    int d   = idx & (DM - 1);
    int row = idx >> 9;
    int l   = row & (L_SEQ - 1);
    float4 w = ((const float4*)convw)[d];
    float acc = convb[d];
    acc = fmaf(x[idx], w.w, acc);
    if (l >= 1) acc = fmaf(x[idx -     DM], w.z, acc);
    if (l >= 2) acc = fmaf(x[idx - 2 * DM], w.y, acc);
    if (l >= 3) acc = fmaf(x[idx - 3 * DM], w.x, acc);
    xc[idx] = acc;
}

// ---------------- tiled transpose xc[row][d] -> xc_t[b][d][l] ----------------
__global__ void k_xct(const float* __restrict__ xc, float* __restrict__ xct) {
    __shared__ float tile[64][65];
    int b = blockIdx.z, lt = blockIdx.y, dtile = blockIdx.x;
    int tx = threadIdx.x & 63, ty = threadIdx.x >> 6;   // ty 0..3
    int l0 = lt * 64, d0 = dtile * 64;
    #pragma unroll
    for (int i = 0; i < 16; ++i) {
        int l = ty + i * 4;
        tile[l][tx] = xc[((size_t)(b * L_SEQ + l0 + l)) * DM + d0 + tx];
    }
    __syncthreads();
    #pragma unroll
    for (int i = 0; i < 16; ++i) {
        int dd = ty + i * 4;
        xct[((size_t)(b * DM + d0 + dd)) * L_SEQ + l0 + tx] = tile[tx][dd];
    }
}

// ---------------- proj1: x_dbl = xc @ Wx^T; split into dt-part / B_t / C_t ----------------
__global__ void k_proj1(const float* __restrict__ xc, const float* __restrict__ WxT,
                        float* __restrict__ xd32, float* __restrict__ Bt,
                        float* __restrict__ Ct) {
    int wv = __builtin_amdgcn_readfirstlane((int)(threadIdx.x >> 6));
    int j  = threadIdx.x & 63;
    int rows_base = blockIdx.x * 32 + wv * 8;      // 256 blocks * 32 rows
    const float* xcrow = xc + (size_t)rows_base * DM;
    float acc[8] = {0.f, 0.f, 0.f, 0.f, 0.f, 0.f, 0.f, 0.f};
    #pragma unroll 4
    for (int d = 0; d < DM; ++d) {
        float w = WxT[d * 64 + j];
        #pragma unroll
        for (int ri = 0; ri < 8; ++ri)
            acc[ri] = fmaf(xcrow[ri * DM + d], w, acc[ri]);
    }
    int b  = rows_base >> 11;
    int l0 = rows_base & (L_SEQ - 1);
    #pragma unroll
    for (int ri = 0; ri < 8; ++ri) {
        int row = rows_base + ri, l = l0 + ri;
        if (j < DR)            xd32[(size_t)row * DR + j] = acc[ri];
        else if (j < DR + DS)  Bt[(size_t)(b * DS + (j - DR)) * L_SEQ + l] = acc[ri];
        else                   Ct[(size_t)(b * DS + (j - DR - DS)) * L_SEQ + l] = acc[ri];
    }
}

// ---------------- proj2 + softplus, writes dt_t[b][d][l] (l-fastest mapping) ----------------
__global__ void k_proj2(const float* __restrict__ xd32, const float* __restrict__ WdtT,
                        const float* __restrict__ dtb, float* __restrict__ dtt) {
    int t  = blockIdx.x * 256 + threadIdx.x;   // over 4M, l fastest
    int l  = t & (L_SEQ - 1);
    int dr = t >> 11;                          // b*DM + d
    int d  = dr & (DM - 1);
    int b  = dr >> 9;
    int row = b * L_SEQ + l;
    const float* xr = xd32 + (size_t)row * DR;
    float z = dtb[d];
    #pragma unroll
    for (int r = 0; r < DR; ++r)
        z = fmaf(xr[r], WdtT[r * DM + d], z);
    float sp = fmaxf(z, 0.f) + log1pf(__expf(-fabsf(z)));
    dtt[t] = sp;
}

// ---------------- pass1: per-chunk (P = prod dA, S = local scan) ----------------
__global__ void __launch_bounds__(256) k_pass1(
        const float* __restrict__ dtt, const float* __restrict__ xct,
        const float* __restrict__ Bt, const float* __restrict__ A_log,
        float* __restrict__ P, float* __restrict__ S) {
    int lane = threadIdx.x & 63;
    int wid  = threadIdx.x >> 6;
    int gw   = blockIdx.x * 4 + wid;           // 0..8191
    int c    = gw & (NCH - 1);
    int d0   = (gw >> 4) & 127;
    int b    = gw >> 11;
    int n    = lane & 15, g = lane >> 4;
    int d    = d0 * 4 + g;
    float a = -__expf(A_log[d0 * 64 + lane]);  // A_log[d][n], coalesced
    size_t chbase = ((size_t)(b * DM + d)) * L_SEQ + c * CL;
    const float4* dtp = (const float4*)(dtt + chbase);
    const float4* xcp = (const float4*)(xct + chbase);
    const float4* Bp  = (const float4*)(Bt + ((size_t)(b * DS + n)) * L_SEQ + c * CL);
    float h = 0.f, Pr = 1.f;
    #pragma unroll 4
    for (int k = 0; k < CL / 4; ++k) {
        float4 d4 = dtp[k], x4 = xcp[k], b4 = Bp[k];
        float dA;
        dA = __expf(d4.x * a); h = fmaf(dA, h, (d4.x * x4.x) * b4.x); Pr *= dA;
        dA = __expf(d4.y * a); h = fmaf(dA, h, (d4.y * x4.y) * b4.y); Pr *= dA;
        dA = __expf(d4.z * a); h = fmaf(dA, h, (d4.z * x4.z) * b4.z); Pr *= dA;
        dA = __expf(d4.w * a); h = fmaf(dA, h, (d4.w * x4.w) * b4.w); Pr *= dA;
    }
    int t = b * 8192 + d0 * 64 + lane;         // = (b*DM+d)*DS + n
    P[c * NBDN + t] = Pr;
    S[c * NBDN + t] = h;
}

// ---------------- pass2: cross-chunk prefix (16 serial steps per chain) ----------------
__global__ void k_pass2(const float* __restrict__ P, const float* __restrict__ S,
                        float* __restrict__ Hin) {
    int t = blockIdx.x * 256 + threadIdx.x;    // 0..32767
    float H = 0.f;
    #pragma unroll
    for (int c = 0; c < NCH; ++c) {
        Hin[c * NBDN + t] = H;
        H = fmaf(P[c * NBDN + t], H, S[c * NBDN + t]);
    }
}

// ---------------- pass3: recompute chunk from Hin, emit y ----------------
__global__ void __launch_bounds__(256) k_pass3(
        const float* __restrict__ dtt, const float* __restrict__ xct,
        const float* __restrict__ Bt, const float* __restrict__ Ct,
        const float* __restrict__ A_log, const float* __restrict__ Dvec,
        const float* __restrict__ Hin, float* __restrict__ out) {
    int lane = threadIdx.x & 63;
    int wid  = threadIdx.x >> 6;
    int gw   = blockIdx.x * 4 + wid;
    int c    = gw & (NCH - 1);
    int d0   = (gw >> 4) & 127;
    int b    = gw >> 11;
    int n    = lane & 15, g = lane >> 4;
    int d    = d0 * 4 + g;
    float a  = -__expf(A_log[d0 * 64 + lane]);
    float Dv = Dvec[d];
    size_t chbase = ((size_t)(b * DM + d)) * L_SEQ + c * CL;
    const float4* dtp = (const float4*)(dtt + chbase);
    const float4* xcp = (const float4*)(xct + chbase);
    const float4* Bp  = (const float4*)(Bt + ((size_t)(b * DS + n)) * L_SEQ + c * CL);
    const float4* Cp  = (const float4*)(Ct + ((size_t)(b * DS + n)) * L_SEQ + c * CL);
    int t = b * 8192 + d0 * 64 + lane;
    float h = Hin[c * NBDN + t];
    float* orow = out + ((size_t)(b * L_SEQ + c * CL)) * DM + d;

    #pragma unroll 2
    for (int k = 0; k < CL / 4; ++k) {
        float4 d4 = dtp[k], x4 = xcp[k], b4 = Bp[k], c4 = Cp[k];
        float dA, p;
#define STEP(E, IDX)                                                          \
        dA = __expf(d4.E * a);                                                \
        h  = fmaf(dA, h, (d4.E * x4.E) * b4.E);                               \
        p  = h * c4.E;                                                        \
        p += __shfl_xor(p, 1); p += __shfl_xor(p, 2);                         \
        p += __shfl_xor(p, 4); p += __shfl_xor(p, 8);                         \
        if (n == 0) orow[(size_t)(k * 4 + IDX) * DM] = fmaf(x4.E, Dv, p);
        STEP(x, 0) STEP(y, 1) STEP(z, 2) STEP(w, 3)
#undef STEP
    }
}

extern "C" void kernel_launch(void* const* d_in, const int* in_sizes, int n_in,
                              void* d_out, int out_size, void* d_ws, size_t ws_size,
                              hipStream_t stream) {
    const float* x      = (const float*)d_in[0];
    const float* A_log  = (const float*)d_in[1];
    const float* Dvec   = (const float*)d_in[2];
    const float* Wx     = (const float*)d_in[3];
    const float* Wdt    = (const float*)d_in[4];
    const float* dtb    = (const float*)d_in[5];
    const float* convw  = (const float*)d_in[6];
    const float* convb  = (const float*)d_in[7];
    float* out = (float*)d_out;
    float* ws  = (float*)d_ws;

    float* xc   = ws + WS_XC;
    float* xct  = ws + WS_XCT;
    float* dtt  = ws + WS_DTT;
    float* xd32 = ws + WS_XD32;
    float* Bt   = ws + WS_BT;
    float* Ct   = ws + WS_CT;
    float* WxT  = ws + WS_WXT;
    float* WdtT = ws + WS_WDTT;
    float* P    = ws + WS_P;      // aliases xc (dead after k_proj1)
    float* S    = ws + WS_S;
    float* Hin  = ws + WS_HIN;

    k_transpose<<<128, 256, 0, stream>>>(Wx, Wdt, WxT, WdtT);
    k_conv<<<16384, 256, 0, stream>>>(x, convw, convb, xc);
    k_xct<<<dim3(8, 32, 4), 256, 0, stream>>>(xc, xct);
    k_proj1<<<256, 256, 0, stream>>>(xc, WxT, xd32, Bt, Ct);
    k_proj2<<<16384, 256, 0, stream>>>(xd32, WdtT, dtb, dtt);
    k_pass1<<<2048, 256, 0, stream>>>(dtt, xct, Bt, A_log, P, S);
    k_pass2<<<128, 256, 0, stream>>>(P, S, Hin);
    k_pass3<<<2048, 256, 0, stream>>>(dtt, xct, Bt, Ct, A_log, Dvec, Hin, out);
}

// Round 3
// 166.637 us; speedup vs baseline: 5.7167x; 1.7362x over previous
//
#include <hip/hip_runtime.h>

#define L_SEQ   2048
#define NBATCH  4
#define DM      512
#define DS      16
#define DR      32
#define NCH     64            // chunks
#define CL      32            // chunk length = L_SEQ/NCH
#define NBDN    32768         // NBATCH*DM*DS chains
#define LOG2E   1.4426950408889634f

// ws layout (float offsets)
#define WS_XC    0            // 4194304  xc row-major [b,l][d]
#define WS_DT    4194304      // 4194304  dt row-major [b,l][d]
#define WS_XDBL  8388608      // 524288   x_dbl [row][64] (dt-part | B | C)
#define WS_WXT   8912896      // 32768
#define WS_WDTT  8945664      // 16384
#define WS_A2    8962048      // 8192     A2[d][n] = -exp(A_log)*log2e
#define WS_P     8970240      // 2097152  P[c][bdn]
#define WS_S     11067392     // 2097152  S[c][bdn]; pass2 rewrites in-place to Hin
// total 13164544 floats = 52.66 MB

// ---------------- weight transposes + A2 precompute ----------------
__global__ void k_transpose(const float* __restrict__ Wx, const float* __restrict__ Wdt,
                            const float* __restrict__ A_log,
                            float* __restrict__ WxT, float* __restrict__ WdtT,
                            float* __restrict__ A2) {
    int idx = blockIdx.x * 256 + threadIdx.x;
    if (idx < DM * 64) {                 // WxT[d][j] = Wx[j][d]
        int d = idx >> 6, j = idx & 63;
        WxT[idx] = Wx[j * DM + d];
    }
    if (idx < DR * DM) {                 // WdtT[r][d] = Wdt[d][r]
        int r = idx >> 9, d = idx & 511;
        WdtT[idx] = Wdt[d * DR + r];
    }
    if (idx < DM * DS)                   // A2[d][n]
        A2[idx] = -__expf(A_log[idx]) * LOG2E;
}

// ---------------- depthwise causal conv1d (K=4), row-major out ----------------
__global__ void k_conv(const float* __restrict__ x, const float* __restrict__ convw,
                       const float* __restrict__ convb, float* __restrict__ xc) {
    int idx = blockIdx.x * 256 + threadIdx.x;      // over 4M elements
    int d   = idx & (DM - 1);
    int row = idx >> 9;
    int l   = row & (L_SEQ - 1);
    float4 w = ((const float4*)convw)[d];
    float acc = convb[d];
    acc = fmaf(x[idx], w.w, acc);
    if (l >= 1) acc = fmaf(x[idx -     DM], w.z, acc);
    if (l >= 2) acc = fmaf(x[idx - 2 * DM], w.y, acc);
    if (l >= 3) acc = fmaf(x[idx - 3 * DM], w.x, acc);
    xc[idx] = acc;
}

// ---------------- proj1: x_dbl[row][j] = sum_d xc[row][d] * Wx[j][d] ----------------
__global__ void k_proj1(const float* __restrict__ xc, const float* __restrict__ WxT,
                        float* __restrict__ xdbl) {
    int wv = __builtin_amdgcn_readfirstlane((int)(threadIdx.x >> 6));
    int j  = threadIdx.x & 63;
    int rows_base = blockIdx.x * 32 + wv * 8;      // 256 blocks * 32 rows
    const float* xcrow = xc + (size_t)rows_base * DM;
    float acc[8] = {0.f, 0.f, 0.f, 0.f, 0.f, 0.f, 0.f, 0.f};
    #pragma unroll 4
    for (int d = 0; d < DM; ++d) {
        float w = WxT[d * 64 + j];
        #pragma unroll
        for (int ri = 0; ri < 8; ++ri)
            acc[ri] = fmaf(xcrow[ri * DM + d], w, acc[ri]);
    }
    #pragma unroll
    for (int ri = 0; ri < 8; ++ri)
        xdbl[(size_t)(rows_base + ri) * 64 + j] = acc[ri];
}

// ---------------- proj2 + softplus: dt[row][d] row-major ----------------
__global__ void k_proj2(const float* __restrict__ xdbl, const float* __restrict__ WdtT,
                        const float* __restrict__ dtb, float* __restrict__ dtw) {
    int idx = blockIdx.x * 256 + threadIdx.x;      // over 4M, d fastest
    int d   = idx & (DM - 1);
    int row = idx >> 9;
    const float* xr = xdbl + (size_t)row * 64;     // dt-part = first 32 cols
    float z = dtb[d];
    #pragma unroll
    for (int r = 0; r < DR; ++r)
        z = fmaf(xr[r], WdtT[r * DM + d], z);
    float sp = fmaxf(z, 0.f) + log1pf(__expf(-fabsf(z)));
    dtw[idx] = sp;
}

// ---------------- pass1: per-chunk local scan; lane = d, states in regs ----------------
__global__ void __launch_bounds__(256) k_pass1(
        const float* __restrict__ dtw, const float* __restrict__ xc,
        const float* __restrict__ xdbl, const float* __restrict__ A2,
        float* __restrict__ P, float* __restrict__ S) {
    int lane = threadIdx.x & 63;
    int w    = threadIdx.x >> 6;
    int blk  = blockIdx.x;                // b(2) | c(6) | half(1)
    int half = blk & 1;
    int c    = (blk >> 1) & 63;
    int b    = blk >> 7;
    int d    = (half * 4 + w) * 64 + lane;

    float a2[16];
    {
        const float4* ap = (const float4*)(A2 + (size_t)d * DS);
        #pragma unroll
        for (int q = 0; q < 4; ++q) {
            float4 v = ap[q];
            a2[q*4+0] = v.x; a2[q*4+1] = v.y; a2[q*4+2] = v.z; a2[q*4+3] = v.w;
        }
    }
    float h[16];
    #pragma unroll
    for (int n = 0; n < 16; ++n) h[n] = 0.f;
    float dtsum = 0.f;

    int l0 = c * CL;
    const float* dtp = dtw  + ((size_t)(b * L_SEQ + l0)) * DM + d;
    const float* xcp = xc   + ((size_t)(b * L_SEQ + l0)) * DM + d;
    const float* bcp = xdbl + ((size_t)(b * L_SEQ + l0)) * 64 + DR;

    #pragma unroll 4
    for (int i = 0; i < CL; ++i) {
        float dt = dtp[(size_t)i * DM];
        float xv = xcp[(size_t)i * DM];
        const float4* Bq = (const float4*)(bcp + (size_t)i * 64);
        float4 B0 = Bq[0], B1 = Bq[1], B2 = Bq[2], B3 = Bq[3];
        float Bs[16] = {B0.x,B0.y,B0.z,B0.w, B1.x,B1.y,B1.z,B1.w,
                        B2.x,B2.y,B2.z,B2.w, B3.x,B3.y,B3.z,B3.w};
        float u = dt * xv;
        dtsum += dt;
        #pragma unroll
        for (int n = 0; n < 16; ++n) {
            float dA = exp2f(dt * a2[n]);
            h[n] = fmaf(dA, h[n], u * Bs[n]);
        }
    }

    size_t tb = (size_t)c * NBDN + ((size_t)(b * DM + d)) * DS;
    float4* Pp = (float4*)(P + tb);
    float4* Sp = (float4*)(S + tb);
    #pragma unroll
    for (int q = 0; q < 4; ++q) {
        float4 pv, sv;
        pv.x = exp2f(a2[q*4+0] * dtsum); pv.y = exp2f(a2[q*4+1] * dtsum);
        pv.z = exp2f(a2[q*4+2] * dtsum); pv.w = exp2f(a2[q*4+3] * dtsum);
        sv.x = h[q*4+0]; sv.y = h[q*4+1]; sv.z = h[q*4+2]; sv.w = h[q*4+3];
        Pp[q] = pv; Sp[q] = sv;
    }
}

// ---------------- pass2: cross-chunk prefix, in-place (S becomes Hin) ----------------
__global__ void k_pass2(const float* __restrict__ P, float* __restrict__ S) {
    int t = blockIdx.x * 256 + threadIdx.x;        // 0..32767
    float H = 0.f;
    #pragma unroll
    for (int c = 0; c < NCH; ++c) {
        float p = P[(size_t)c * NBDN + t];
        float s = S[(size_t)c * NBDN + t];
        S[(size_t)c * NBDN + t] = H;               // Hin for chunk c
        H = fmaf(p, H, s);
    }
}

// ---------------- pass3: recompute chunk from Hin, emit y row-major ----------------
__global__ void __launch_bounds__(256) k_pass3(
        const float* __restrict__ dtw, const float* __restrict__ xc,
        const float* __restrict__ xdbl, const float* __restrict__ A2,
        const float* __restrict__ Dvec, const float* __restrict__ Hin,
        float* __restrict__ out) {
    int lane = threadIdx.x & 63;
    int w    = threadIdx.x >> 6;
    int blk  = blockIdx.x;
    int half = blk & 1;
    int c    = (blk >> 1) & 63;
    int b    = blk >> 7;
    int d    = (half * 4 + w) * 64 + lane;

    float a2[16];
    {
        const float4* ap = (const float4*)(A2 + (size_t)d * DS);
        #pragma unroll
        for (int q = 0; q < 4; ++q) {
            float4 v = ap[q];
            a2[q*4+0] = v.x; a2[q*4+1] = v.y; a2[q*4+2] = v.z; a2[q*4+3] = v.w;
        }
    }
    float Dv = Dvec[d];
    float h[16];
    {
        const float4* hp = (const float4*)(Hin + (size_t)c * NBDN + ((size_t)(b * DM + d)) * DS);
        #pragma unroll
        for (int q = 0; q < 4; ++q) {
            float4 v = hp[q];
            h[q*4+0] = v.x; h[q*4+1] = v.y; h[q*4+2] = v.z; h[q*4+3] = v.w;
        }
    }

    int l0 = c * CL;
    const float* dtp = dtw  + ((size_t)(b * L_SEQ + l0)) * DM + d;
    const float* xcp = xc   + ((size_t)(b * L_SEQ + l0)) * DM + d;
    const float* bcp = xdbl + ((size_t)(b * L_SEQ + l0)) * 64 + DR;
    float* op = out + ((size_t)(b * L_SEQ + l0)) * DM + d;

    #pragma unroll 4
    for (int i = 0; i < CL; ++i) {
        float dt = dtp[(size_t)i * DM];
        float xv = xcp[(size_t)i * DM];
        const float4* Bq = (const float4*)(bcp + (size_t)i * 64);
        float4 B0 = Bq[0], B1 = Bq[1], B2 = Bq[2], B3 = Bq[3];
        float4 C0 = Bq[4], C1 = Bq[5], C2 = Bq[6], C3 = Bq[7];
        float Bs[16] = {B0.x,B0.y,B0.z,B0.w, B1.x,B1.y,B1.z,B1.w,
                        B2.x,B2.y,B2.z,B2.w, B3.x,B3.y,B3.z,B3.w};
        float Cs[16] = {C0.x,C0.y,C0.z,C0.w, C1.x,C1.y,C1.z,C1.w,
                        C2.x,C2.y,C2.z,C2.w, C3.x,C3.y,C3.z,C3.w};
        float u = dt * xv;
        float y = xv * Dv;
        #pragma unroll
        for (int n = 0; n < 16; ++n) {
            float dA = exp2f(dt * a2[n]);
            h[n] = fmaf(dA, h[n], u * Bs[n]);
            y = fmaf(h[n], Cs[n], y);
        }
        op[(size_t)i * DM] = y;
    }
}

extern "C" void kernel_launch(void* const* d_in, const int* in_sizes, int n_in,
                              void* d_out, int out_size, void* d_ws, size_t ws_size,
                              hipStream_t stream) {
    const float* x      = (const float*)d_in[0];
    const float* A_log  = (const float*)d_in[1];
    const float* Dvec   = (const float*)d_in[2];
    const float* Wx     = (const float*)d_in[3];
    const float* Wdt    = (const float*)d_in[4];
    const float* dtb    = (const float*)d_in[5];
    const float* convw  = (const float*)d_in[6];
    const float* convb  = (const float*)d_in[7];
    float* out = (float*)d_out;
    float* ws  = (float*)d_ws;

    float* xc   = ws + WS_XC;
    float* dtw  = ws + WS_DT;
    float* xdbl = ws + WS_XDBL;
    float* WxT  = ws + WS_WXT;
    float* WdtT = ws + WS_WDTT;
    float* A2   = ws + WS_A2;
    float* P    = ws + WS_P;
    float* S    = ws + WS_S;

    k_transpose<<<128, 256, 0, stream>>>(Wx, Wdt, A_log, WxT, WdtT, A2);
    k_conv<<<16384, 256, 0, stream>>>(x, convw, convb, xc);
    k_proj1<<<256, 256, 0, stream>>>(xc, WxT, xdbl);
    k_proj2<<<16384, 256, 0, stream>>>(xdbl, WdtT, dtb, dtw);
    k_pass1<<<512, 256, 0, stream>>>(dtw, xc, xdbl, A2, P, S);
    k_pass2<<<128, 256, 0, stream>>>(P, S);
    k_pass3<<<512, 256, 0, stream>>>(dtw, xc, xdbl, A2, Dvec, S, out);
}

// Round 4
// 128.951 us; speedup vs baseline: 7.3874x; 1.2922x over previous
//
#include <hip/hip_runtime.h>

#define L_SEQ   2048
#define NBATCH  4
#define DM      512
#define DS      16
#define DR      32
#define NROWS   8192
#define NBDN    32768         // NBATCH*DM*DS chains
#define LOG2E   1.4426950408889634f

// ws layout (float offsets)
#define WS_XC    0            // 4194304  xc row-major [b,l][d]
#define WS_DT    4194304      // 4194304  dt row-major [b,l][d]
#define WS_XDBL  8388608      // 524288   x_dbl [row][64] (dt-part | B | C)
#define WS_WXT   8912896      // 32768
#define WS_WDTT  8945664      // 16384
#define WS_A2    8962048      // 8192     A2[d][n] = -exp(A_log)*log2e
#define WS_P     8970240      // NCH*32768  P[c][bdn]  (proj1 partials alias this)
// S follows P at WS_P + NCH*NBDN; pass2 rewrites S in-place to Hin.
// NCH=64 : total 13164544 floats = 52.7 MB
// NCH=128: total 17358848 floats = 69.4 MB (used only if ws_size allows)

// ---------------- weight transposes + A2 precompute ----------------
__global__ void k_transpose(const float* __restrict__ Wx, const float* __restrict__ Wdt,
                            const float* __restrict__ A_log,
                            float* __restrict__ WxT, float* __restrict__ WdtT,
                            float* __restrict__ A2) {
    int idx = blockIdx.x * 256 + threadIdx.x;
    if (idx < DM * 64) {                 // WxT[d][j] = Wx[j][d]
        int d = idx >> 6, j = idx & 63;
        WxT[idx] = Wx[j * DM + d];
    }
    if (idx < DR * DM) {                 // WdtT[r][d] = Wdt[d][r]
        int r = idx >> 9, d = idx & 511;
        WdtT[idx] = Wdt[d * DR + r];
    }
    if (idx < DM * DS)                   // A2[d][n]
        A2[idx] = -__expf(A_log[idx]) * LOG2E;
}

// ---------------- depthwise causal conv1d (K=4), float4 over d ----------------
__global__ void k_conv(const float* __restrict__ x, const float* __restrict__ convw,
                       const float* __restrict__ convb, float* __restrict__ xc) {
    int idx = blockIdx.x * 256 + threadIdx.x;      // 0..1048575
    int dq  = idx & 127;
    int row = idx >> 7;
    int l   = row & (L_SEQ - 1);
    const float4* wp = (const float4*)convw;       // [d] -> (k0,k1,k2,k3)
    float4 w0 = wp[dq * 4 + 0], w1 = wp[dq * 4 + 1];
    float4 w2 = wp[dq * 4 + 2], w3 = wp[dq * 4 + 3];
    float4 acc = ((const float4*)convb)[dq];
    const float* xr = x + (size_t)row * DM + dq * 4;
    float4 xv = *(const float4*)xr;
    acc.x = fmaf(xv.x, w0.w, acc.x); acc.y = fmaf(xv.y, w1.w, acc.y);
    acc.z = fmaf(xv.z, w2.w, acc.z); acc.w = fmaf(xv.w, w3.w, acc.w);
    if (l >= 1) {
        xv = *(const float4*)(xr - DM);
        acc.x = fmaf(xv.x, w0.z, acc.x); acc.y = fmaf(xv.y, w1.z, acc.y);
        acc.z = fmaf(xv.z, w2.z, acc.z); acc.w = fmaf(xv.w, w3.z, acc.w);
    }
    if (l >= 2) {
        xv = *(const float4*)(xr - 2 * DM);
        acc.x = fmaf(xv.x, w0.y, acc.x); acc.y = fmaf(xv.y, w1.y, acc.y);
        acc.z = fmaf(xv.z, w2.y, acc.z); acc.w = fmaf(xv.w, w3.y, acc.w);
    }
    if (l >= 3) {
        xv = *(const float4*)(xr - 3 * DM);
        acc.x = fmaf(xv.x, w0.x, acc.x); acc.y = fmaf(xv.y, w1.x, acc.y);
        acc.z = fmaf(xv.z, w2.x, acc.z); acc.w = fmaf(xv.w, w3.x, acc.w);
    }
    *(float4*)(xc + (size_t)row * DM + dq * 4) = acc;
}

// ---------------- proj1a: K-split x4 partial GEMM ----------------
__global__ void k_proj1a(const float* __restrict__ xc, const float* __restrict__ WxT,
                         float* __restrict__ part) {
    int wv = __builtin_amdgcn_readfirstlane((int)(threadIdx.x >> 6));
    int j  = threadIdx.x & 63;
    int ks = blockIdx.x & 3;
    int rows_base = (blockIdx.x >> 2) * 32 + wv * 8;
    int k0 = ks * 128;
    const float* xcrow = xc + (size_t)rows_base * DM + k0;
    const float* wp    = WxT + (size_t)k0 * 64 + j;
    float acc[8] = {0.f, 0.f, 0.f, 0.f, 0.f, 0.f, 0.f, 0.f};
    #pragma unroll 8
    for (int d = 0; d < 128; ++d) {
        float w = wp[d * 64];
        #pragma unroll
        for (int ri = 0; ri < 8; ++ri)
            acc[ri] = fmaf(xcrow[ri * DM + d], w, acc[ri]);
    }
    float* pp = part + (size_t)ks * (NROWS * 64) + (size_t)rows_base * 64 + j;
    #pragma unroll
    for (int ri = 0; ri < 8; ++ri)
        pp[ri * 64] = acc[ri];
}

// ---------------- proj1b: reduce 4 partials -> xdbl ----------------
__global__ void k_proj1b(const float* __restrict__ part, float* __restrict__ xdbl) {
    int idx = blockIdx.x * 256 + threadIdx.x;      // 0..524287
    xdbl[idx] = (part[idx] + part[idx + 524288])
              + (part[idx + 2 * 524288] + part[idx + 3 * 524288]);
}

// ---------------- proj2 + softplus: 4 outputs/thread, float4 weights ----------------
__global__ void k_proj2(const float* __restrict__ xdbl, const float* __restrict__ WdtT,
                        const float* __restrict__ dtb, float* __restrict__ dtw) {
    int idx = blockIdx.x * 256 + threadIdx.x;      // 0..1048575
    int dq  = idx & 127;
    int row = __builtin_amdgcn_readfirstlane(idx >> 7);   // wave-uniform
    const float* xr = xdbl + (size_t)row * 64;
    float4 z = ((const float4*)dtb)[dq];
    #pragma unroll
    for (int r = 0; r < DR; ++r) {
        float xv = xr[r];
        float4 w4 = *(const float4*)(WdtT + r * DM + dq * 4);
        z.x = fmaf(xv, w4.x, z.x); z.y = fmaf(xv, w4.y, z.y);
        z.z = fmaf(xv, w4.z, z.z); z.w = fmaf(xv, w4.w, z.w);
    }
    float4 sp;
    sp.x = fmaxf(z.x, 0.f) + log1pf(__expf(-fabsf(z.x)));
    sp.y = fmaxf(z.y, 0.f) + log1pf(__expf(-fabsf(z.y)));
    sp.z = fmaxf(z.z, 0.f) + log1pf(__expf(-fabsf(z.z)));
    sp.w = fmaxf(z.w, 0.f) + log1pf(__expf(-fabsf(z.w)));
    *(float4*)(dtw + (size_t)row * DM + dq * 4) = sp;
}

// ---------------- pass1: per-chunk local scan; lane = d, states in regs ----------------
template<int NCH>
__global__ void __launch_bounds__(256) k_pass1(
        const float* __restrict__ dtw, const float* __restrict__ xc,
        const float* __restrict__ xdbl, const float* __restrict__ A2,
        float* __restrict__ P, float* __restrict__ S) {
    constexpr int CL = L_SEQ / NCH;
    int lane = threadIdx.x & 63;
    int w    = threadIdx.x >> 6;
    int half = blockIdx.x & 1;
    int c    = blockIdx.x >> 1;
    int b    = blockIdx.y;
    int d    = (half * 4 + w) * 64 + lane;

    float a2[16];
    {
        const float4* ap = (const float4*)(A2 + (size_t)d * DS);
        #pragma unroll
        for (int q = 0; q < 4; ++q) {
            float4 v = ap[q];
            a2[q*4+0] = v.x; a2[q*4+1] = v.y; a2[q*4+2] = v.z; a2[q*4+3] = v.w;
        }
    }
    float h[16];
    #pragma unroll
    for (int n = 0; n < 16; ++n) h[n] = 0.f;
    float dtsum = 0.f;

    int l0 = c * CL;
    const float* dtp = dtw  + ((size_t)(b * L_SEQ + l0)) * DM + d;
    const float* xcp = xc   + ((size_t)(b * L_SEQ + l0)) * DM + d;
    const float* bcp = xdbl + ((size_t)(b * L_SEQ + l0)) * 64 + DR;

    #pragma unroll 4
    for (int i = 0; i < CL; ++i) {
        float dt = dtp[(size_t)i * DM];
        float xv = xcp[(size_t)i * DM];
        const float4* Bq = (const float4*)(bcp + (size_t)i * 64);
        float4 B0 = Bq[0], B1 = Bq[1], B2 = Bq[2], B3 = Bq[3];
        float Bs[16] = {B0.x,B0.y,B0.z,B0.w, B1.x,B1.y,B1.z,B1.w,
                        B2.x,B2.y,B2.z,B2.w, B3.x,B3.y,B3.z,B3.w};
        float u = dt * xv;
        dtsum += dt;
        #pragma unroll
        for (int n = 0; n < 16; ++n) {
            float dA = exp2f(dt * a2[n]);
            h[n] = fmaf(dA, h[n], u * Bs[n]);
        }
    }

    size_t tb = (size_t)c * NBDN + ((size_t)(b * DM + d)) * DS;
    float4* Pp = (float4*)(P + tb);
    float4* Sp = (float4*)(S + tb);
    #pragma unroll
    for (int q = 0; q < 4; ++q) {
        float4 pv, sv;
        pv.x = exp2f(a2[q*4+0] * dtsum); pv.y = exp2f(a2[q*4+1] * dtsum);
        pv.z = exp2f(a2[q*4+2] * dtsum); pv.w = exp2f(a2[q*4+3] * dtsum);
        sv.x = h[q*4+0]; sv.y = h[q*4+1]; sv.z = h[q*4+2]; sv.w = h[q*4+3];
        Pp[q] = pv; Sp[q] = sv;
    }
}

// ---------------- pass2: cross-chunk prefix, in-place (S becomes Hin) ----------------
template<int NCH>
__global__ void k_pass2(const float* __restrict__ P, float* __restrict__ S) {
    int t = blockIdx.x * 256 + threadIdx.x;        // 0..32767
    float H = 0.f;
    #pragma unroll 8
    for (int c = 0; c < NCH; ++c) {
        float p = P[(size_t)c * NBDN + t];
        float s = S[(size_t)c * NBDN + t];
        S[(size_t)c * NBDN + t] = H;               // Hin for chunk c
        H = fmaf(p, H, s);
    }
}

// ---------------- pass3: recompute chunk from Hin, emit y row-major ----------------
template<int NCH>
__global__ void __launch_bounds__(256) k_pass3(
        const float* __restrict__ dtw, const float* __restrict__ xc,
        const float* __restrict__ xdbl, const float* __restrict__ A2,
        const float* __restrict__ Dvec, const float* __restrict__ Hin,
        float* __restrict__ out) {
    constexpr int CL = L_SEQ / NCH;
    int lane = threadIdx.x & 63;
    int w    = threadIdx.x >> 6;
    int half = blockIdx.x & 1;
    int c    = blockIdx.x >> 1;
    int b    = blockIdx.y;
    int d    = (half * 4 + w) * 64 + lane;

    float a2[16];
    {
        const float4* ap = (const float4*)(A2 + (size_t)d * DS);
        #pragma unroll
        for (int q = 0; q < 4; ++q) {
            float4 v = ap[q];
            a2[q*4+0] = v.x; a2[q*4+1] = v.y; a2[q*4+2] = v.z; a2[q*4+3] = v.w;
        }
    }
    float Dv = Dvec[d];
    float h[16];
    {
        const float4* hp = (const float4*)(Hin + (size_t)c * NBDN + ((size_t)(b * DM + d)) * DS);
        #pragma unroll
        for (int q = 0; q < 4; ++q) {
            float4 v = hp[q];
            h[q*4+0] = v.x; h[q*4+1] = v.y; h[q*4+2] = v.z; h[q*4+3] = v.w;
        }
    }

    int l0 = c * CL;
    const float* dtp = dtw  + ((size_t)(b * L_SEQ + l0)) * DM + d;
    const float* xcp = xc   + ((size_t)(b * L_SEQ + l0)) * DM + d;
    const float* bcp = xdbl + ((size_t)(b * L_SEQ + l0)) * 64 + DR;
    float* op = out + ((size_t)(b * L_SEQ + l0)) * DM + d;

    #pragma unroll 4
    for (int i = 0; i < CL; ++i) {
        float dt = dtp[(size_t)i * DM];
        float xv = xcp[(size_t)i * DM];
        const float4* Bq = (const float4*)(bcp + (size_t)i * 64);
        float4 B0 = Bq[0], B1 = Bq[1], B2 = Bq[2], B3 = Bq[3];
        float4 C0 = Bq[4], C1 = Bq[5], C2 = Bq[6], C3 = Bq[7];
        float Bs[16] = {B0.x,B0.y,B0.z,B0.w, B1.x,B1.y,B1.z,B1.w,
                        B2.x,B2.y,B2.z,B2.w, B3.x,B3.y,B3.z,B3.w};
        float Cs[16] = {C0.x,C0.y,C0.z,C0.w, C1.x,C1.y,C1.z,C1.w,
                        C2.x,C2.y,C2.z,C2.w, C3.x,C3.y,C3.z,C3.w};
        float u = dt * xv;
        float y = xv * Dv;
        #pragma unroll
        for (int n = 0; n < 16; ++n) {
            float dA = exp2f(dt * a2[n]);
            h[n] = fmaf(dA, h[n], u * Bs[n]);
            y = fmaf(h[n], Cs[n], y);
        }
        op[(size_t)i * DM] = y;
    }
}

extern "C" void kernel_launch(void* const* d_in, const int* in_sizes, int n_in,
                              void* d_out, int out_size, void* d_ws, size_t ws_size,
                              hipStream_t stream) {
    const float* x      = (const float*)d_in[0];
    const float* A_log  = (const float*)d_in[1];
    const float* Dvec   = (const float*)d_in[2];
    const float* Wx     = (const float*)d_in[3];
    const float* Wdt    = (const float*)d_in[4];
    const float* dtb    = (const float*)d_in[5];
    const float* convw  = (const float*)d_in[6];
    const float* convb  = (const float*)d_in[7];
    float* out = (float*)d_out;
    float* ws  = (float*)d_ws;

    float* xc   = ws + WS_XC;
    float* dtw  = ws + WS_DT;
    float* xdbl = ws + WS_XDBL;
    float* WxT  = ws + WS_WXT;
    float* WdtT = ws + WS_WDTT;
    float* A2   = ws + WS_A2;
    float* P    = ws + WS_P;

    k_transpose<<<128, 256, 0, stream>>>(Wx, Wdt, A_log, WxT, WdtT, A2);
    k_conv<<<4096, 256, 0, stream>>>(x, convw, convb, xc);
    k_proj1a<<<1024, 256, 0, stream>>>(xc, WxT, P);        // partials alias P
    k_proj1b<<<2048, 256, 0, stream>>>(P, xdbl);
    k_proj2<<<4096, 256, 0, stream>>>(xdbl, WdtT, dtb, dtw);

    const size_t needBig = (size_t)(WS_P + (size_t)2 * 128 * NBDN) * sizeof(float);
    if (ws_size >= needBig) {
        float* S = ws + WS_P + (size_t)128 * NBDN;
        k_pass1<128><<<dim3(256, 4), 256, 0, stream>>>(dtw, xc, xdbl, A2, P, S);
        k_pass2<128><<<128, 256, 0, stream>>>(P, S);
        k_pass3<128><<<dim3(256, 4), 256, 0, stream>>>(dtw, xc, xdbl, A2, Dvec, S, out);
    } else {
        float* S = ws + WS_P + (size_t)64 * NBDN;
        k_pass1<64><<<dim3(128, 4), 256, 0, stream>>>(dtw, xc, xdbl, A2, P, S);
        k_pass2<64><<<128, 256, 0, stream>>>(P, S);
        k_pass3<64><<<dim3(128, 4), 256, 0, stream>>>(dtw, xc, xdbl, A2, Dvec, S, out);
    }
}